// Round 5
// baseline (3013.219 us; speedup 1.0000x reference)
//
#include <hip/hip_runtime.h>
#include <hip/hip_bf16.h>

#define NN 50000
#define NE 800000
#define C 128
#define H 16

typedef unsigned int u32;
typedef unsigned short u16;

// ---------- silu + 7 cubic B-spline bases, closed form ----------
// knots at -2.5 + 0.5j; t = (x+2.5)*2; cell c = floor(t); u local.
// B_j nonzero iff c in {j..j+3}; piece polys verified against Cox-de-Boor.
__device__ __forceinline__ void feat8f(float x, float* fv) {
  fv[0] = x / (1.f + __expf(-x));
  float t = (x + 2.5f) * 2.0f;
  float cf = floorf(t);
  int c = (int)cf;
  float u = t - cf;
  float u2 = u * u, u3 = u2 * u;
  const float k6 = 1.f / 6.f;
  float P0 = u3 * k6;
  float P1 = (1.f + 3.f * u + 3.f * u2 - 3.f * u3) * k6;
  float P2 = (4.f - 6.f * u2 + 3.f * u3) * k6;
  float om = 1.f - u;
  float P3 = om * om * om * k6;
  bool valid = (t >= 0.f) && (t < 10.f);
#pragma unroll
  for (int j = 0; j < 7; ++j) {
    float b = 0.f;
    b = (c == j)     ? P0 : b;
    b = (c == j + 1) ? P1 : b;
    b = (c == j + 2) ? P2 : b;
    b = (c == j + 3) ? P3 : b;
    fv[1 + j] = valid ? b : 0.f;
  }
}

__device__ __forceinline__ u16 f2bf(float v) {
  u32 b = __float_as_uint(v);
  return (u16)((b + 0x7fffu + ((b >> 16) & 1u)) >> 16);  // RNE
}

__device__ __forceinline__ float dot8(uint4 r, const float* f, float acc) {
  u32 w0 = r.x, w1 = r.y, w2 = r.z, w3 = r.w;
  acc = fmaf(__uint_as_float(w0 << 16), f[0], acc);
  acc = fmaf(__uint_as_float(w0 & 0xffff0000u), f[1], acc);
  acc = fmaf(__uint_as_float(w1 << 16), f[2], acc);
  acc = fmaf(__uint_as_float(w1 & 0xffff0000u), f[3], acc);
  acc = fmaf(__uint_as_float(w2 << 16), f[4], acc);
  acc = fmaf(__uint_as_float(w2 & 0xffff0000u), f[5], acc);
  acc = fmaf(__uint_as_float(w3 << 16), f[6], acc);
  acc = fmaf(__uint_as_float(w3 & 0xffff0000u), f[7], acc);
  return acc;
}

// ---------- prep: Wt transpose (f32) + bf16 packed KAN weights ----------
__global__ void prep_kernel(const float* __restrict__ W,
                            const float* __restrict__ bw0, const float* __restrict__ sw0,
                            const float* __restrict__ sc0,
                            const float* __restrict__ bw1, const float* __restrict__ sw1,
                            const float* __restrict__ sc1,
                            float* __restrict__ Wt, u16* __restrict__ p0bf,
                            u16* __restrict__ p1bf) {
  int i = blockIdx.x * blockDim.x + threadIdx.x;
  if (i < C * C) {
    int k = i >> 7, o = i & 127;
    Wt[k * C + o] = W[o * C + k];
  }
  if (i < H * C * 8) {
    int of = i >> 3, j = i & 7;
    float v = (j == 0) ? bw0[of] : sw0[of * 7 + (j - 1)] * sc0[of];
    p0bf[i] = f2bf(v);
  }
  if (i < C * H * 8) {
    int of = i >> 3, j = i & 7;
    float v = (j == 0) ? bw1[of] : sw1[of * 7 + (j - 1)] * sc1[of];
    p1bf[i] = f2bf(v);
  }
}

// ---------- in-degree count ----------
__global__ void count_kernel(const int* __restrict__ dst, int* __restrict__ cnt) {
  int e = blockIdx.x * blockDim.x + threadIdx.x;
  if (e < NE) atomicAdd(&cnt[dst[e]], 1);
}

// ---------- hierarchical exclusive scan ----------
__global__ void scan1(const int* __restrict__ cnt, int* __restrict__ excl,
                      int* __restrict__ bsums, int n) {
  int i = blockIdx.x * 256 + threadIdx.x;
  int v = (i < n) ? cnt[i] : 0;
  int lane = threadIdx.x & 63, wid = threadIdx.x >> 6;
  int s = v;
#pragma unroll
  for (int o = 1; o < 64; o <<= 1) {
    int t = __shfl_up(s, o, 64);
    if (lane >= o) s += t;
  }
  __shared__ int wsum[4];
  if (lane == 63) wsum[wid] = s;
  __syncthreads();
  int woff = 0;
  for (int w = 0; w < wid; ++w) woff += wsum[w];
  if (i < n) excl[i] = woff + s - v;
  if (threadIdx.x == 255) bsums[blockIdx.x] = woff + s;
}

__global__ void scan2(int* __restrict__ bsums, int nb) {
  int i = threadIdx.x;
  int v = (i < nb) ? bsums[i] : 0;
  int lane = threadIdx.x & 63, wid = threadIdx.x >> 6;
  int s = v;
#pragma unroll
  for (int o = 1; o < 64; o <<= 1) {
    int t = __shfl_up(s, o, 64);
    if (lane >= o) s += t;
  }
  __shared__ int wsum[4];
  if (lane == 63) wsum[wid] = s;
  __syncthreads();
  int woff = 0;
  for (int w = 0; w < wid; ++w) woff += wsum[w];
  if (i < nb) bsums[i] = woff + s - v;
}

__global__ void scan3(const int* __restrict__ excl, const int* __restrict__ bsums,
                      const int* __restrict__ cnt, int* __restrict__ row_start,
                      float* __restrict__ dinv, int n) {
  int i = blockIdx.x * 256 + threadIdx.x;
  if (i < n) {
    row_start[i] = excl[i] + bsums[blockIdx.x];
    dinv[i] = rsqrtf((float)(cnt[i] + 1));
  }
  if (blockIdx.x == 0 && threadIdx.x == 0) row_start[n] = NE;
}

// ---------- CSR fill; csrw = dinv[src]*dinv[dst] ----------
__global__ void fill_kernel(const int* __restrict__ src, const int* __restrict__ dst,
                            const int* __restrict__ row_start, const float* __restrict__ dinv,
                            int* __restrict__ fillcnt, int* __restrict__ csr,
                            float* __restrict__ csrw) {
  int e = blockIdx.x * blockDim.x + threadIdx.x;
  if (e < NE) {
    int d = dst[e];
    int s = src[e];
    int p = atomicAdd(&fillcnt[d], 1);
    int slot = row_start[d] + p;
    csr[slot] = s;
    csrw[slot] = dinv[s] * dinv[d];
  }
}

// ---------- aggregation: ax[node][c] ----------
__global__ __launch_bounds__(256, 8) void agg_kernel(
    const float* __restrict__ x, const int* __restrict__ csr,
    const float* __restrict__ csrw, const int* __restrict__ row_start,
    const float* __restrict__ dinv, float* __restrict__ ax) {
  const int c = threadIdx.x & 127;
  const int node = blockIdx.x * 2 + (threadIdx.x >> 7);
  const int e0 = row_start[node], e1 = row_start[node + 1];
  const float dn = dinv[node];
  float a = x[(size_t)node * C + c] * (dn * dn);
  int e = e0;
  for (; e + 4 <= e1; e += 4) {
    const int s0 = csr[e], s1 = csr[e + 1], s2 = csr[e + 2], s3 = csr[e + 3];
    const float w0 = csrw[e], w1 = csrw[e + 1], w2 = csrw[e + 2], w3 = csrw[e + 3];
    a += x[(size_t)s0 * C + c] * w0;
    a += x[(size_t)s1 * C + c] * w1;
    a += x[(size_t)s2 * C + c] * w2;
    a += x[(size_t)s3 * C + c] * w3;
  }
  for (; e < e1; ++e) a += x[(size_t)csr[e] * C + c] * csrw[e];
  ax[(size_t)node * C + c] = a;
}

// ---------- GEMV as tiled GEMM, IN-PLACE on ax: h = ax @ W^T ----------
// 64 nodes x 128 outs per block; each block only touches its own 64 rows.
__global__ __launch_bounds__(256) void gemm128(const float* __restrict__ Wt,
                                               float* __restrict__ axh) {
  __shared__ float Xs[64][129];   // 33 KB
  __shared__ float Ws[32][132];   // 16.9 KB (132: rows 528B, 16B-aligned)
  const int tid = threadIdx.x;
  const int n0 = blockIdx.x * 64;
#pragma unroll
  for (int it = 0; it < 8; ++it) {
    int idx = it * 1024 + tid * 4;
    int n = idx >> 7, k = idx & 127;
    float4 v = make_float4(0.f, 0.f, 0.f, 0.f);
    if (n0 + n < NN) v = *(const float4*)&axh[(size_t)(n0 + n) * C + k];
    *(float4*)&Xs[n][k] = v;
  }
  const int nt = tid & 15, ot = tid >> 4;
  float4 accA[4], accB[4];
#pragma unroll
  for (int d = 0; d < 4; ++d) {
    accA[d] = make_float4(0.f, 0.f, 0.f, 0.f);
    accB[d] = make_float4(0.f, 0.f, 0.f, 0.f);
  }
  for (int k0 = 0; k0 < 128; k0 += 32) {
    __syncthreads();
#pragma unroll
    for (int it = 0; it < 4; ++it) {
      int idx = it * 1024 + tid * 4;
      int k = idx >> 7, oo = idx & 127;
      *(float4*)&Ws[k][oo] = *(const float4*)&Wt[(k0 + k) * C + oo];
    }
    __syncthreads();
#pragma unroll
    for (int k = 0; k < 32; ++k) {
      float4 w0 = *(const float4*)&Ws[k][ot * 8];
      float4 w1 = *(const float4*)&Ws[k][ot * 8 + 4];
#pragma unroll
      for (int d = 0; d < 4; ++d) {
        float xv = Xs[nt * 4 + d][k0 + k];
        accA[d].x += xv * w0.x; accA[d].y += xv * w0.y;
        accA[d].z += xv * w0.z; accA[d].w += xv * w0.w;
        accB[d].x += xv * w1.x; accB[d].y += xv * w1.y;
        accB[d].z += xv * w1.z; accB[d].w += xv * w1.w;
      }
    }
  }
#pragma unroll
  for (int d = 0; d < 4; ++d) {
    int node = n0 + nt * 4 + d;
    if (node < NN) {
      *(float4*)&axh[(size_t)node * C + ot * 8] = accA[d];
      *(float4*)&axh[(size_t)node * C + ot * 8 + 4] = accB[d];
    }
  }
}

// ---------- KAN stack: bf16 weights stationary in LDS, one node per wave ----------
// P0s: [j][f][tpair] u32, 32 KB, naturally bank-spread (f in low addr bits).
// P1s: [o][j^ (o&7)][tpair] u32, 32 KB, XOR-swizzled (j alone would hit 1 bank).
__global__ __launch_bounds__(512, 4) void kanB(
    const float* __restrict__ h, const float* __restrict__ bias,
    const u16* __restrict__ p0bf, const u16* __restrict__ p1bf,
    float* __restrict__ out) {
  __shared__ u32 P0s[8192];
  __shared__ u32 P1s[8192];
  const int tid = threadIdx.x;
  {
    const uint4* g0 = (const uint4*)p0bf;  // 2048 records of 16B
    const uint4* g1 = (const uint4*)p1bf;
    uint4* s0 = (uint4*)P0s;
    uint4* s1 = (uint4*)P1s;
    for (int r = tid; r < 2048; r += 512) {
      s0[r] = g0[r];
      int o = r >> 4, j = r & 15;
      int rs = (r & ~15) | (j ^ (o & 7));
      s1[rs] = g1[r];
    }
  }
  __syncthreads();
  const int o = tid & 63;
  const int wave = tid >> 6;
  const int nwaves = gridDim.x * 8;
  const float bLo = bias[o], bHi = bias[o + 64];
  const int swz = o & 7;
  for (int node = blockIdx.x * 8 + wave; node < NN; node += nwaves) {
    float fa[8], fb[8];
    feat8f(h[(size_t)node * C + o] + bLo, fa);
    feat8f(h[(size_t)node * C + o + 64] + bHi, fb);
    // KAN0 partials: lane o covers features f=o and f=o+64
    float pj[16];
#pragma unroll
    for (int j = 0; j < 16; ++j) {
      uint4 ra = *(const uint4*)&P0s[j * 512 + o * 4];
      uint4 rb = *(const uint4*)&P0s[j * 512 + (o + 64) * 4];
      float a = dot8(ra, fa, 0.f);
      pj[j] = dot8(rb, fb, a);
    }
    // full butterfly: every lane ends with all 16 hidden sums
#pragma unroll
    for (int j = 0; j < 16; ++j) {
      float v = pj[j];
      v += __shfl_xor(v, 1, 64);
      v += __shfl_xor(v, 2, 64);
      v += __shfl_xor(v, 4, 64);
      v += __shfl_xor(v, 8, 64);
      v += __shfl_xor(v, 16, 64);
      v += __shfl_xor(v, 32, 64);
      pj[j] = v;
    }
    // lane o computes feat of hidden j = o&15 (static-index select chain)
    float hsel = pj[0];
#pragma unroll
    for (int k = 1; k < 16; ++k) hsel = ((o & 15) == k) ? pj[k] : hsel;
    float fh[8];
    feat8f(hsel, fh);
    // KAN1: broadcast feat1[j][*] from lane j via readlane
    float accLo = 0.f, accHi = 0.f;
#pragma unroll
    for (int j = 0; j < 16; ++j) {
      float fj[8];
#pragma unroll
      for (int t = 0; t < 8; ++t)
        fj[t] = __int_as_float(__builtin_amdgcn_readlane(__float_as_int(fh[t]), j));
      uint4 ra = *(const uint4*)&P1s[o * 64 + (j ^ swz) * 4];
      uint4 rb = *(const uint4*)&P1s[(o + 64) * 64 + (j ^ swz) * 4];
      accLo = dot8(ra, fj, accLo);
      accHi = dot8(rb, fj, accHi);
    }
    out[(size_t)node * C + o] = accLo;
    out[(size_t)node * C + o + 64] = accHi;
  }
}

extern "C" void kernel_launch(void* const* d_in, const int* in_sizes, int n_in,
                              void* d_out, int out_size, void* d_ws, size_t ws_size,
                              hipStream_t stream) {
  const float* x   = (const float*)d_in[0];
  const int*   ei  = (const int*)d_in[1];
  const float* gw  = (const float*)d_in[2];
  const float* gb  = (const float*)d_in[3];
  const float* bw0 = (const float*)d_in[4];
  const float* sw0 = (const float*)d_in[5];
  const float* sc0 = (const float*)d_in[6];
  const float* bw1 = (const float*)d_in[7];
  const float* sw1 = (const float*)d_in[8];
  const float* sc1 = (const float*)d_in[9];
  float* out = (float*)d_out;

  // workspace ~33 MB
  char* p = (char*)d_ws;
  float* Wt = (float*)p;      p += C * C * 4;          // 64 KB
  u16* p0bf = (u16*)p;        p += H * C * 8 * 2;      // 32 KB
  u16* p1bf = (u16*)p;        p += C * H * 8 * 2;      // 32 KB
  float* dinv = (float*)p;    p += NN * 4;
  int* cnt = (int*)p;         p += NN * 4;
  int* excl = (int*)p;        p += NN * 4;
  int* fillcnt = (int*)p;     p += NN * 4;
  int* bsums = (int*)p;       p += 256 * 4;
  int* row_start = (int*)p;   p += (NN + 4) * 4;
  int* csr = (int*)p;         p += (size_t)NE * 4;     // 3.2 MB
  float* csrw = (float*)p;    p += (size_t)NE * 4;     // 3.2 MB
  float* axh = (float*)p;     p += (size_t)NN * C * 4; // 25.6 MB (ax, then h in-place)

  const int* src = ei;
  const int* dst = ei + NE;

  hipMemsetAsync(cnt, 0, NN * 4, stream);
  hipMemsetAsync(fillcnt, 0, NN * 4, stream);

  prep_kernel<<<64, 256, 0, stream>>>(gw, bw0, sw0, sc0, bw1, sw1, sc1, Wt, p0bf, p1bf);
  count_kernel<<<(NE + 255) / 256, 256, 0, stream>>>(dst, cnt);
  scan1<<<196, 256, 0, stream>>>(cnt, excl, bsums, NN);
  scan2<<<1, 256, 0, stream>>>(bsums, 196);
  scan3<<<196, 256, 0, stream>>>(excl, bsums, cnt, row_start, dinv, NN);
  fill_kernel<<<(NE + 255) / 256, 256, 0, stream>>>(src, dst, row_start, dinv, fillcnt, csr, csrw);
  agg_kernel<<<NN / 2, 256, 0, stream>>>(x, csr, csrw, row_start, dinv, axh);
  gemm128<<<(NN + 63) / 64, 256, 0, stream>>>(Wt, axh);
  kanB<<<1024, 512, 0, stream>>>(axh, gb, p0bf, p1bf, out);
}

// Round 6
// 2715.224 us; speedup vs baseline: 1.1097x; 1.1097x over previous
//
#include <hip/hip_runtime.h>
#include <hip/hip_bf16.h>

#define NN 50000
#define NE 800000
#define C 128
#define H 16

typedef unsigned int u32;
typedef unsigned short u16;

// ---------- silu + 7 cubic B-spline bases, closed form, NAMED outputs ----------
// knots at -2.5 + 0.5j; t=(x+2.5)*2; cell c=floor(t), local u. Validated r5.
__device__ __forceinline__ void feat8s(float x, float& s, float& g0, float& g1,
                                       float& g2, float& g3, float& g4, float& g5,
                                       float& g6) {
  s = x / (1.f + __expf(-x));
  float t = (x + 2.5f) * 2.0f;
  float cf = floorf(t);
  int c = (int)cf;
  float u = t - cf;
  float u2 = u * u, u3 = u2 * u;
  const float k6 = 1.f / 6.f;
  float P0 = u3 * k6;
  float P1 = (1.f + 3.f * u + 3.f * u2 - 3.f * u3) * k6;
  float P2 = (4.f - 6.f * u2 + 3.f * u3) * k6;
  float om = 1.f - u;
  float P3 = om * om * om * k6;
  bool valid = (t >= 0.f) && (t < 10.f);
#define SPJ(G, J)                                   \
  {                                                 \
    float b = 0.f;                                  \
    b = (c == (J)) ? P0 : b;                        \
    b = (c == (J) + 1) ? P1 : b;                    \
    b = (c == (J) + 2) ? P2 : b;                    \
    b = (c == (J) + 3) ? P3 : b;                    \
    G = valid ? b : 0.f;                            \
  }
  SPJ(g0, 0) SPJ(g1, 1) SPJ(g2, 2) SPJ(g3, 3) SPJ(g4, 4) SPJ(g5, 5) SPJ(g6, 6)
#undef SPJ
}

__device__ __forceinline__ u16 f2bf(float v) {
  u32 b = __float_as_uint(v);
  return (u16)((b + 0x7fffu + ((b >> 16) & 1u)) >> 16);  // RNE
}

// dot of 8 bf16 weights (packed in uint4) with 8 named floats
__device__ __forceinline__ float dot8s(uint4 r, float f0, float f1, float f2,
                                       float f3, float f4, float f5, float f6,
                                       float f7, float acc) {
  acc = fmaf(__uint_as_float(r.x << 16), f0, acc);
  acc = fmaf(__uint_as_float(r.x & 0xffff0000u), f1, acc);
  acc = fmaf(__uint_as_float(r.y << 16), f2, acc);
  acc = fmaf(__uint_as_float(r.y & 0xffff0000u), f3, acc);
  acc = fmaf(__uint_as_float(r.z << 16), f4, acc);
  acc = fmaf(__uint_as_float(r.z & 0xffff0000u), f5, acc);
  acc = fmaf(__uint_as_float(r.w << 16), f6, acc);
  acc = fmaf(__uint_as_float(r.w & 0xffff0000u), f7, acc);
  return acc;
}

#define RL(x, J) __int_as_float(__builtin_amdgcn_readlane(__float_as_int(x), (J)))
#define REP16(M) M(0) M(1) M(2) M(3) M(4) M(5) M(6) M(7) M(8) M(9) M(10) M(11) M(12) M(13) M(14) M(15)

// ---------- prep: Wt transpose (f32) + bf16 packed KAN weights ----------
__global__ void prep_kernel(const float* __restrict__ W,
                            const float* __restrict__ bw0, const float* __restrict__ sw0,
                            const float* __restrict__ sc0,
                            const float* __restrict__ bw1, const float* __restrict__ sw1,
                            const float* __restrict__ sc1,
                            float* __restrict__ Wt, u16* __restrict__ p0bf,
                            u16* __restrict__ p1bf) {
  int i = blockIdx.x * blockDim.x + threadIdx.x;
  if (i < C * C) {
    int k = i >> 7, o = i & 127;
    Wt[k * C + o] = W[o * C + k];
  }
  if (i < H * C * 8) {
    int of = i >> 3, j = i & 7;
    float v = (j == 0) ? bw0[of] : sw0[of * 7 + (j - 1)] * sc0[of];
    p0bf[i] = f2bf(v);
  }
  if (i < C * H * 8) {
    int of = i >> 3, j = i & 7;
    float v = (j == 0) ? bw1[of] : sw1[of * 7 + (j - 1)] * sc1[of];
    p1bf[i] = f2bf(v);
  }
}

// ---------- in-degree count ----------
__global__ void count_kernel(const int* __restrict__ dst, int* __restrict__ cnt) {
  int e = blockIdx.x * blockDim.x + threadIdx.x;
  if (e < NE) atomicAdd(&cnt[dst[e]], 1);
}

// ---------- hierarchical exclusive scan ----------
__global__ void scan1(const int* __restrict__ cnt, int* __restrict__ excl,
                      int* __restrict__ bsums, int n) {
  int i = blockIdx.x * 256 + threadIdx.x;
  int v = (i < n) ? cnt[i] : 0;
  int lane = threadIdx.x & 63, wid = threadIdx.x >> 6;
  int s = v;
#pragma unroll
  for (int o = 1; o < 64; o <<= 1) {
    int t = __shfl_up(s, o, 64);
    if (lane >= o) s += t;
  }
  __shared__ int wsum[4];
  if (lane == 63) wsum[wid] = s;
  __syncthreads();
  int woff = 0;
  for (int w = 0; w < wid; ++w) woff += wsum[w];
  if (i < n) excl[i] = woff + s - v;
  if (threadIdx.x == 255) bsums[blockIdx.x] = woff + s;
}

__global__ void scan2(int* __restrict__ bsums, int nb) {
  int i = threadIdx.x;
  int v = (i < nb) ? bsums[i] : 0;
  int lane = threadIdx.x & 63, wid = threadIdx.x >> 6;
  int s = v;
#pragma unroll
  for (int o = 1; o < 64; o <<= 1) {
    int t = __shfl_up(s, o, 64);
    if (lane >= o) s += t;
  }
  __shared__ int wsum[4];
  if (lane == 63) wsum[wid] = s;
  __syncthreads();
  int woff = 0;
  for (int w = 0; w < wid; ++w) woff += wsum[w];
  if (i < nb) bsums[i] = woff + s - v;
}

__global__ void scan3(const int* __restrict__ excl, const int* __restrict__ bsums,
                      const int* __restrict__ cnt, int* __restrict__ row_start,
                      float* __restrict__ dinv, int n) {
  int i = blockIdx.x * 256 + threadIdx.x;
  if (i < n) {
    row_start[i] = excl[i] + bsums[blockIdx.x];
    dinv[i] = rsqrtf((float)(cnt[i] + 1));
  }
  if (blockIdx.x == 0 && threadIdx.x == 0) row_start[n] = NE;
}

// ---------- CSR fill; csrw = dinv[src]*dinv[dst] ----------
__global__ void fill_kernel(const int* __restrict__ src, const int* __restrict__ dst,
                            const int* __restrict__ row_start, const float* __restrict__ dinv,
                            int* __restrict__ fillcnt, int* __restrict__ csr,
                            float* __restrict__ csrw) {
  int e = blockIdx.x * blockDim.x + threadIdx.x;
  if (e < NE) {
    int d = dst[e];
    int s = src[e];
    int p = atomicAdd(&fillcnt[d], 1);
    int slot = row_start[d] + p;
    csr[slot] = s;
    csrw[slot] = dinv[s] * dinv[d];
  }
}

// ---------- aggregation ----------
__global__ __launch_bounds__(256, 8) void agg_kernel(
    const float* __restrict__ x, const int* __restrict__ csr,
    const float* __restrict__ csrw, const int* __restrict__ row_start,
    const float* __restrict__ dinv, float* __restrict__ ax) {
  const int c = threadIdx.x & 127;
  const int node = blockIdx.x * 2 + (threadIdx.x >> 7);
  const int e0 = row_start[node], e1 = row_start[node + 1];
  const float dn = dinv[node];
  float a = x[(size_t)node * C + c] * (dn * dn);
  int e = e0;
  for (; e + 4 <= e1; e += 4) {
    const int s0 = csr[e], s1 = csr[e + 1], s2 = csr[e + 2], s3 = csr[e + 3];
    const float w0 = csrw[e], w1 = csrw[e + 1], w2 = csrw[e + 2], w3 = csrw[e + 3];
    a += x[(size_t)s0 * C + c] * w0;
    a += x[(size_t)s1 * C + c] * w1;
    a += x[(size_t)s2 * C + c] * w2;
    a += x[(size_t)s3 * C + c] * w3;
  }
  for (; e < e1; ++e) a += x[(size_t)csr[e] * C + c] * csrw[e];
  ax[(size_t)node * C + c] = a;
}

// ---------- GEMV as tiled GEMM, in-place: h = ax @ W^T ----------
__global__ __launch_bounds__(256) void gemm128(const float* __restrict__ Wt,
                                               float* __restrict__ axh) {
  __shared__ float Xs[64][129];
  __shared__ float Ws[32][132];
  const int tid = threadIdx.x;
  const int n0 = blockIdx.x * 64;
#pragma unroll
  for (int it = 0; it < 8; ++it) {
    int idx = it * 1024 + tid * 4;
    int n = idx >> 7, k = idx & 127;
    float4 v = make_float4(0.f, 0.f, 0.f, 0.f);
    if (n0 + n < NN) v = *(const float4*)&axh[(size_t)(n0 + n) * C + k];
    *(float4*)&Xs[n][k] = v;
  }
  const int nt = tid & 15, ot = tid >> 4;
  float4 accA[4], accB[4];
#pragma unroll
  for (int d = 0; d < 4; ++d) {
    accA[d] = make_float4(0.f, 0.f, 0.f, 0.f);
    accB[d] = make_float4(0.f, 0.f, 0.f, 0.f);
  }
  for (int k0 = 0; k0 < 128; k0 += 32) {
    __syncthreads();
#pragma unroll
    for (int it = 0; it < 4; ++it) {
      int idx = it * 1024 + tid * 4;
      int k = idx >> 7, oo = idx & 127;
      *(float4*)&Ws[k][oo] = *(const float4*)&Wt[(k0 + k) * C + oo];
    }
    __syncthreads();
#pragma unroll
    for (int k = 0; k < 32; ++k) {
      float4 w0 = *(const float4*)&Ws[k][ot * 8];
      float4 w1 = *(const float4*)&Ws[k][ot * 8 + 4];
#pragma unroll
      for (int d = 0; d < 4; ++d) {
        float xv = Xs[nt * 4 + d][k0 + k];
        accA[d].x += xv * w0.x; accA[d].y += xv * w0.y;
        accA[d].z += xv * w0.z; accA[d].w += xv * w0.w;
        accB[d].x += xv * w1.x; accB[d].y += xv * w1.y;
        accB[d].z += xv * w1.z; accB[d].w += xv * w1.w;
      }
    }
  }
#pragma unroll
  for (int d = 0; d < 4; ++d) {
    int node = n0 + nt * 4 + d;
    if (node < NN) {
      *(float4*)&axh[(size_t)node * C + ot * 8] = accA[d];
      *(float4*)&axh[(size_t)node * C + ot * 8 + 4] = accB[d];
    }
  }
}

// ---------- KAN stack: LDS-stationary bf16 weights, one node/wave, NO arrays ----------
// P0s: [j][f] uint4 records (f consecutive -> conflict-free b128 reads)
// P1s: [j][o] uint4 records (o consecutive -> conflict-free b128 reads)
__global__ __launch_bounds__(512, 4) void kanC(
    const float* __restrict__ h, const float* __restrict__ bias,
    const u16* __restrict__ p0bf, const u16* __restrict__ p1bf,
    float* __restrict__ out) {
  __shared__ u32 P0s[8192];   // 32 KB: uint4 idx j*128 + f
  __shared__ u32 P1s[8192];   // 32 KB: uint4 idx j*128 + o
  const int tid = threadIdx.x;
  {
    const uint4* g0 = (const uint4*)p0bf;  // record r = j*128 + f (matches)
    const uint4* g1 = (const uint4*)p1bf;  // record r = o*16 + j -> transpose
    uint4* s0 = (uint4*)P0s;
    uint4* s1 = (uint4*)P1s;
    for (int r = tid; r < 2048; r += 512) {
      s0[r] = g0[r];
      int o = r >> 4, j = r & 15;
      s1[j * 128 + o] = g1[r];
    }
  }
  __syncthreads();
  const int o = tid & 63;
  const int wave = tid >> 6;
  const int j16 = o & 15;
  const float bLo = bias[o], bHi = bias[o + 64];
  for (int node = blockIdx.x * 8 + wave; node < NN; node += 4096) {
    float fa0, fa1, fa2, fa3, fa4, fa5, fa6, fa7;
    float fb0, fb1, fb2, fb3, fb4, fb5, fb6, fb7;
    feat8s(h[(size_t)node * C + o] + bLo, fa0, fa1, fa2, fa3, fa4, fa5, fa6, fa7);
    feat8s(h[(size_t)node * C + o + 64] + bHi, fb0, fb1, fb2, fb3, fb4, fb5, fb6, fb7);
    // KAN0 partials: lane o covers features f=o and f=o+64 (named p0..p15)
#define K0(J)                                                                  \
    float p##J;                                                                \
    {                                                                          \
      uint4 ra = *(const uint4*)&P0s[(J) * 512 + o * 4];                       \
      uint4 rb = *(const uint4*)&P0s[(J) * 512 + (o + 64) * 4];                \
      p##J = dot8s(ra, fa0, fa1, fa2, fa3, fa4, fa5, fa6, fa7, 0.f);           \
      p##J = dot8s(rb, fb0, fb1, fb2, fb3, fb4, fb5, fb6, fb7, p##J);          \
    }
    REP16(K0)
#undef K0
    // butterfly reduce: every lane ends with all 16 hidden sums (named)
#define BF(J)                                                                  \
    {                                                                          \
      float v = p##J;                                                          \
      v += __shfl_xor(v, 1, 64);  v += __shfl_xor(v, 2, 64);                   \
      v += __shfl_xor(v, 4, 64);  v += __shfl_xor(v, 8, 64);                   \
      v += __shfl_xor(v, 16, 64); v += __shfl_xor(v, 32, 64);                  \
      p##J = v;                                                                \
    }
    REP16(BF)
#undef BF
    // lane o computes features of hidden value j16 = o&15
    float hsel = p0;
    hsel = (j16 == 1) ? p1 : hsel;   hsel = (j16 == 2) ? p2 : hsel;
    hsel = (j16 == 3) ? p3 : hsel;   hsel = (j16 == 4) ? p4 : hsel;
    hsel = (j16 == 5) ? p5 : hsel;   hsel = (j16 == 6) ? p6 : hsel;
    hsel = (j16 == 7) ? p7 : hsel;   hsel = (j16 == 8) ? p8 : hsel;
    hsel = (j16 == 9) ? p9 : hsel;   hsel = (j16 == 10) ? p10 : hsel;
    hsel = (j16 == 11) ? p11 : hsel; hsel = (j16 == 12) ? p12 : hsel;
    hsel = (j16 == 13) ? p13 : hsel; hsel = (j16 == 14) ? p14 : hsel;
    hsel = (j16 == 15) ? p15 : hsel;
    float fh0, fh1, fh2, fh3, fh4, fh5, fh6, fh7;
    feat8s(hsel, fh0, fh1, fh2, fh3, fh4, fh5, fh6, fh7);
    // KAN1: broadcast hidden-j features from lane j via readlane (uniform)
    float accLo = 0.f, accHi = 0.f;
#define K1(J)                                                                  \
    {                                                                          \
      float q0 = RL(fh0, J), q1 = RL(fh1, J), q2 = RL(fh2, J), q3 = RL(fh3, J);\
      float q4 = RL(fh4, J), q5 = RL(fh5, J), q6 = RL(fh6, J), q7 = RL(fh7, J);\
      uint4 ra = *(const uint4*)&P1s[(J) * 512 + o * 4];                       \
      uint4 rb = *(const uint4*)&P1s[(J) * 512 + (o + 64) * 4];                \
      accLo = dot8s(ra, q0, q1, q2, q3, q4, q5, q6, q7, accLo);                \
      accHi = dot8s(rb, q0, q1, q2, q3, q4, q5, q6, q7, accHi);                \
    }
    REP16(K1)
#undef K1
    out[(size_t)node * C + o] = accLo;
    out[(size_t)node * C + o + 64] = accHi;
  }
}

extern "C" void kernel_launch(void* const* d_in, const int* in_sizes, int n_in,
                              void* d_out, int out_size, void* d_ws, size_t ws_size,
                              hipStream_t stream) {
  const float* x   = (const float*)d_in[0];
  const int*   ei  = (const int*)d_in[1];
  const float* gw  = (const float*)d_in[2];
  const float* gb  = (const float*)d_in[3];
  const float* bw0 = (const float*)d_in[4];
  const float* sw0 = (const float*)d_in[5];
  const float* sc0 = (const float*)d_in[6];
  const float* bw1 = (const float*)d_in[7];
  const float* sw1 = (const float*)d_in[8];
  const float* sc1 = (const float*)d_in[9];
  float* out = (float*)d_out;

  char* p = (char*)d_ws;
  float* Wt = (float*)p;      p += C * C * 4;
  u16* p0bf = (u16*)p;        p += H * C * 8 * 2;
  u16* p1bf = (u16*)p;        p += C * H * 8 * 2;
  float* dinv = (float*)p;    p += NN * 4;
  int* cnt = (int*)p;         p += NN * 4;
  int* excl = (int*)p;        p += NN * 4;
  int* fillcnt = (int*)p;     p += NN * 4;
  int* bsums = (int*)p;       p += 256 * 4;
  int* row_start = (int*)p;   p += (NN + 4) * 4;
  int* csr = (int*)p;         p += (size_t)NE * 4;
  float* csrw = (float*)p;    p += (size_t)NE * 4;
  float* axh = (float*)p;     p += (size_t)NN * C * 4;

  const int* src = ei;
  const int* dst = ei + NE;

  hipMemsetAsync(cnt, 0, NN * 4, stream);
  hipMemsetAsync(fillcnt, 0, NN * 4, stream);

  prep_kernel<<<64, 256, 0, stream>>>(gw, bw0, sw0, sc0, bw1, sw1, sc1, Wt, p0bf, p1bf);
  count_kernel<<<(NE + 255) / 256, 256, 0, stream>>>(dst, cnt);
  scan1<<<196, 256, 0, stream>>>(cnt, excl, bsums, NN);
  scan2<<<1, 256, 0, stream>>>(bsums, 196);
  scan3<<<196, 256, 0, stream>>>(excl, bsums, cnt, row_start, dinv, NN);
  fill_kernel<<<(NE + 255) / 256, 256, 0, stream>>>(src, dst, row_start, dinv, fillcnt, csr, csrw);
  agg_kernel<<<NN / 2, 256, 0, stream>>>(x, csr, csrw, row_start, dinv, axh);
  gemm128<<<(NN + 63) / 64, 256, 0, stream>>>(Wt, axh);
  kanC<<<512, 512, 0, stream>>>(axh, gb, p0bf, p1bf, out);
}

// Round 7
// 2370.350 us; speedup vs baseline: 1.2712x; 1.1455x over previous
//
#include <hip/hip_runtime.h>
#include <hip/hip_bf16.h>

#define NN 50000
#define NE 800000
#define C 128
#define H 16

typedef unsigned int u32;
typedef unsigned short u16;

// ---------- silu + 7 cubic B-spline bases, closed form, NAMED outputs ----------
// knots at -2.5 + 0.5j; t=(x+2.5)*2; cell c=floor(t), local u. Validated r5.
__device__ __forceinline__ void feat8s(float x, float& s, float& g0, float& g1,
                                       float& g2, float& g3, float& g4, float& g5,
                                       float& g6) {
  s = x / (1.f + __expf(-x));
  float t = (x + 2.5f) * 2.0f;
  float cf = floorf(t);
  int c = (int)cf;
  float u = t - cf;
  float u2 = u * u, u3 = u2 * u;
  const float k6 = 1.f / 6.f;
  float P0 = u3 * k6;
  float P1 = (1.f + 3.f * u + 3.f * u2 - 3.f * u3) * k6;
  float P2 = (4.f - 6.f * u2 + 3.f * u3) * k6;
  float om = 1.f - u;
  float P3 = om * om * om * k6;
  bool valid = (t >= 0.f) && (t < 10.f);
#define SPJ(G, J)                                   \
  {                                                 \
    float b = 0.f;                                  \
    b = (c == (J)) ? P0 : b;                        \
    b = (c == (J) + 1) ? P1 : b;                    \
    b = (c == (J) + 2) ? P2 : b;                    \
    b = (c == (J) + 3) ? P3 : b;                    \
    G = valid ? b : 0.f;                            \
  }
  SPJ(g0, 0) SPJ(g1, 1) SPJ(g2, 2) SPJ(g3, 3) SPJ(g4, 4) SPJ(g5, 5) SPJ(g6, 6)
#undef SPJ
}

__device__ __forceinline__ u16 f2bf(float v) {
  u32 b = __float_as_uint(v);
  return (u16)((b + 0x7fffu + ((b >> 16) & 1u)) >> 16);  // RNE
}

// dot of 8 bf16 weights (packed in uint4) with 8 named floats
__device__ __forceinline__ float dot8s(uint4 r, float f0, float f1, float f2,
                                       float f3, float f4, float f5, float f6,
                                       float f7, float acc) {
  acc = fmaf(__uint_as_float(r.x << 16), f0, acc);
  acc = fmaf(__uint_as_float(r.x & 0xffff0000u), f1, acc);
  acc = fmaf(__uint_as_float(r.y << 16), f2, acc);
  acc = fmaf(__uint_as_float(r.y & 0xffff0000u), f3, acc);
  acc = fmaf(__uint_as_float(r.z << 16), f4, acc);
  acc = fmaf(__uint_as_float(r.z & 0xffff0000u), f5, acc);
  acc = fmaf(__uint_as_float(r.w << 16), f6, acc);
  acc = fmaf(__uint_as_float(r.w & 0xffff0000u), f7, acc);
  return acc;
}

#define RL(x, J) __int_as_float(__builtin_amdgcn_readlane(__float_as_int(x), (J)))
#define REP16(M) M(0) M(1) M(2) M(3) M(4) M(5) M(6) M(7) M(8) M(9) M(10) M(11) M(12) M(13) M(14) M(15)

// ---------- prep: Wt transpose (f32) + bf16 packed KAN weights ----------
__global__ void prep_kernel(const float* __restrict__ W,
                            const float* __restrict__ bw0, const float* __restrict__ sw0,
                            const float* __restrict__ sc0,
                            const float* __restrict__ bw1, const float* __restrict__ sw1,
                            const float* __restrict__ sc1,
                            float* __restrict__ Wt, u16* __restrict__ p0bf,
                            u16* __restrict__ p1bf) {
  int i = blockIdx.x * blockDim.x + threadIdx.x;
  if (i < C * C) {
    int k = i >> 7, o = i & 127;
    Wt[k * C + o] = W[o * C + k];
  }
  if (i < H * C * 8) {
    int of = i >> 3, j = i & 7;
    float v = (j == 0) ? bw0[of] : sw0[of * 7 + (j - 1)] * sc0[of];
    p0bf[i] = f2bf(v);
  }
  if (i < C * H * 8) {
    int of = i >> 3, j = i & 7;
    float v = (j == 0) ? bw1[of] : sw1[of * 7 + (j - 1)] * sc1[of];
    p1bf[i] = f2bf(v);
  }
}

// ---------- in-degree count ----------
__global__ void count_kernel(const int* __restrict__ dst, int* __restrict__ cnt) {
  int e = blockIdx.x * blockDim.x + threadIdx.x;
  if (e < NE) atomicAdd(&cnt[dst[e]], 1);
}

// ---------- hierarchical exclusive scan ----------
__global__ void scan1(const int* __restrict__ cnt, int* __restrict__ excl,
                      int* __restrict__ bsums, int n) {
  int i = blockIdx.x * 256 + threadIdx.x;
  int v = (i < n) ? cnt[i] : 0;
  int lane = threadIdx.x & 63, wid = threadIdx.x >> 6;
  int s = v;
#pragma unroll
  for (int o = 1; o < 64; o <<= 1) {
    int t = __shfl_up(s, o, 64);
    if (lane >= o) s += t;
  }
  __shared__ int wsum[4];
  if (lane == 63) wsum[wid] = s;
  __syncthreads();
  int woff = 0;
  for (int w = 0; w < wid; ++w) woff += wsum[w];
  if (i < n) excl[i] = woff + s - v;
  if (threadIdx.x == 255) bsums[blockIdx.x] = woff + s;
}

__global__ void scan2(int* __restrict__ bsums, int nb) {
  int i = threadIdx.x;
  int v = (i < nb) ? bsums[i] : 0;
  int lane = threadIdx.x & 63, wid = threadIdx.x >> 6;
  int s = v;
#pragma unroll
  for (int o = 1; o < 64; o <<= 1) {
    int t = __shfl_up(s, o, 64);
    if (lane >= o) s += t;
  }
  __shared__ int wsum[4];
  if (lane == 63) wsum[wid] = s;
  __syncthreads();
  int woff = 0;
  for (int w = 0; w < wid; ++w) woff += wsum[w];
  if (i < nb) bsums[i] = woff + s - v;
}

__global__ void scan3(const int* __restrict__ excl, const int* __restrict__ bsums,
                      const int* __restrict__ cnt, int* __restrict__ row_start,
                      float* __restrict__ dinv, int n) {
  int i = blockIdx.x * 256 + threadIdx.x;
  if (i < n) {
    row_start[i] = excl[i] + bsums[blockIdx.x];
    dinv[i] = rsqrtf((float)(cnt[i] + 1));
  }
  if (blockIdx.x == 0 && threadIdx.x == 0) row_start[n] = NE;
}

// ---------- CSR fill; csrw = dinv[src]*dinv[dst] ----------
__global__ void fill_kernel(const int* __restrict__ src, const int* __restrict__ dst,
                            const int* __restrict__ row_start, const float* __restrict__ dinv,
                            int* __restrict__ fillcnt, int* __restrict__ csr,
                            float* __restrict__ csrw) {
  int e = blockIdx.x * blockDim.x + threadIdx.x;
  if (e < NE) {
    int d = dst[e];
    int s = src[e];
    int p = atomicAdd(&fillcnt[d], 1);
    int slot = row_start[d] + p;
    csr[slot] = s;
    csrw[slot] = dinv[s] * dinv[d];
  }
}

// ---------- aggregation ----------
__global__ __launch_bounds__(256, 8) void agg_kernel(
    const float* __restrict__ x, const int* __restrict__ csr,
    const float* __restrict__ csrw, const int* __restrict__ row_start,
    const float* __restrict__ dinv, float* __restrict__ ax) {
  const int c = threadIdx.x & 127;
  const int node = blockIdx.x * 2 + (threadIdx.x >> 7);
  const int e0 = row_start[node], e1 = row_start[node + 1];
  const float dn = dinv[node];
  float a = x[(size_t)node * C + c] * (dn * dn);
  int e = e0;
  for (; e + 4 <= e1; e += 4) {
    const int s0 = csr[e], s1 = csr[e + 1], s2 = csr[e + 2], s3 = csr[e + 3];
    const float w0 = csrw[e], w1 = csrw[e + 1], w2 = csrw[e + 2], w3 = csrw[e + 3];
    a += x[(size_t)s0 * C + c] * w0;
    a += x[(size_t)s1 * C + c] * w1;
    a += x[(size_t)s2 * C + c] * w2;
    a += x[(size_t)s3 * C + c] * w3;
  }
  for (; e < e1; ++e) a += x[(size_t)csr[e] * C + c] * csrw[e];
  ax[(size_t)node * C + c] = a;
}

// ---------- GEMV as tiled GEMM, in-place: h = ax @ W^T ----------
__global__ __launch_bounds__(256) void gemm128(const float* __restrict__ Wt,
                                               float* __restrict__ axh) {
  __shared__ float Xs[64][129];
  __shared__ float Ws[32][132];
  const int tid = threadIdx.x;
  const int n0 = blockIdx.x * 64;
#pragma unroll
  for (int it = 0; it < 8; ++it) {
    int idx = it * 1024 + tid * 4;
    int n = idx >> 7, k = idx & 127;
    float4 v = make_float4(0.f, 0.f, 0.f, 0.f);
    if (n0 + n < NN) v = *(const float4*)&axh[(size_t)(n0 + n) * C + k];
    *(float4*)&Xs[n][k] = v;
  }
  const int nt = tid & 15, ot = tid >> 4;
  float4 accA[4], accB[4];
#pragma unroll
  for (int d = 0; d < 4; ++d) {
    accA[d] = make_float4(0.f, 0.f, 0.f, 0.f);
    accB[d] = make_float4(0.f, 0.f, 0.f, 0.f);
  }
  for (int k0 = 0; k0 < 128; k0 += 32) {
    __syncthreads();
#pragma unroll
    for (int it = 0; it < 4; ++it) {
      int idx = it * 1024 + tid * 4;
      int k = idx >> 7, oo = idx & 127;
      *(float4*)&Ws[k][oo] = *(const float4*)&Wt[(k0 + k) * C + oo];
    }
    __syncthreads();
#pragma unroll
    for (int k = 0; k < 32; ++k) {
      float4 w0 = *(const float4*)&Ws[k][ot * 8];
      float4 w1 = *(const float4*)&Ws[k][ot * 8 + 4];
#pragma unroll
      for (int d = 0; d < 4; ++d) {
        float xv = Xs[nt * 4 + d][k0 + k];
        accA[d].x += xv * w0.x; accA[d].y += xv * w0.y;
        accA[d].z += xv * w0.z; accA[d].w += xv * w0.w;
        accB[d].x += xv * w1.x; accB[d].y += xv * w1.y;
        accB[d].z += xv * w1.z; accB[d].w += xv * w1.w;
      }
    }
  }
#pragma unroll
  for (int d = 0; d < 4; ++d) {
    int node = n0 + nt * 4 + d;
    if (node < NN) {
      *(float4*)&axh[(size_t)node * C + ot * 8] = accA[d];
      *(float4*)&axh[(size_t)node * C + ot * 8 + 4] = accB[d];
    }
  }
}

// ---------- KAN stack: LDS-stationary bf16 weights, one node/wave, NO arrays ----------
// P0s: [j][f] uint4 records (f consecutive -> conflict-free b128 reads)
// P1s: [j][o] uint4 records (o consecutive -> conflict-free b128 reads)
// NOTE: no min-blocks clause! (512,4) forced a 64-VGPR cap -> 3.2 GB spill
// traffic (r5/r6). LDS=64KB already caps residency at 2 blocks/CU -> 128 VGPR.
__global__ __launch_bounds__(512) void kanC(
    const float* __restrict__ h, const float* __restrict__ bias,
    const u16* __restrict__ p0bf, const u16* __restrict__ p1bf,
    float* __restrict__ out) {
  __shared__ u32 P0s[8192];   // 32 KB: uint4 idx j*128 + f
  __shared__ u32 P1s[8192];   // 32 KB: uint4 idx j*128 + o
  const int tid = threadIdx.x;
  {
    const uint4* g0 = (const uint4*)p0bf;  // record r = j*128 + f (matches)
    const uint4* g1 = (const uint4*)p1bf;  // record r = o*16 + j -> transpose
    uint4* s0 = (uint4*)P0s;
    uint4* s1 = (uint4*)P1s;
    for (int r = tid; r < 2048; r += 512) {
      s0[r] = g0[r];
      int o = r >> 4, j = r & 15;
      s1[j * 128 + o] = g1[r];
    }
  }
  __syncthreads();
  const int o = tid & 63;
  const int wave = tid >> 6;
  const int j16 = o & 15;
  const float bLo = bias[o], bHi = bias[o + 64];
  for (int node = blockIdx.x * 8 + wave; node < NN; node += 4096) {
    float fa0, fa1, fa2, fa3, fa4, fa5, fa6, fa7;
    float fb0, fb1, fb2, fb3, fb4, fb5, fb6, fb7;
    feat8s(h[(size_t)node * C + o] + bLo, fa0, fa1, fa2, fa3, fa4, fa5, fa6, fa7);
    feat8s(h[(size_t)node * C + o + 64] + bHi, fb0, fb1, fb2, fb3, fb4, fb5, fb6, fb7);
    // KAN0 partials: lane o covers features f=o and f=o+64 (named p0..p15)
#define K0(J)                                                                  \
    float p##J;                                                                \
    {                                                                          \
      uint4 ra = *(const uint4*)&P0s[(J) * 512 + o * 4];                       \
      uint4 rb = *(const uint4*)&P0s[(J) * 512 + (o + 64) * 4];                \
      p##J = dot8s(ra, fa0, fa1, fa2, fa3, fa4, fa5, fa6, fa7, 0.f);           \
      p##J = dot8s(rb, fb0, fb1, fb2, fb3, fb4, fb5, fb6, fb7, p##J);          \
    }
    REP16(K0)
#undef K0
    // butterfly reduce: every lane ends with all 16 hidden sums (named)
#define BF(J)                                                                  \
    {                                                                          \
      float v = p##J;                                                          \
      v += __shfl_xor(v, 1, 64);  v += __shfl_xor(v, 2, 64);                   \
      v += __shfl_xor(v, 4, 64);  v += __shfl_xor(v, 8, 64);                   \
      v += __shfl_xor(v, 16, 64); v += __shfl_xor(v, 32, 64);                  \
      p##J = v;                                                                \
    }
    REP16(BF)
#undef BF
    // lane o computes features of hidden value j16 = o&15
    float hsel = p0;
    hsel = (j16 == 1) ? p1 : hsel;   hsel = (j16 == 2) ? p2 : hsel;
    hsel = (j16 == 3) ? p3 : hsel;   hsel = (j16 == 4) ? p4 : hsel;
    hsel = (j16 == 5) ? p5 : hsel;   hsel = (j16 == 6) ? p6 : hsel;
    hsel = (j16 == 7) ? p7 : hsel;   hsel = (j16 == 8) ? p8 : hsel;
    hsel = (j16 == 9) ? p9 : hsel;   hsel = (j16 == 10) ? p10 : hsel;
    hsel = (j16 == 11) ? p11 : hsel; hsel = (j16 == 12) ? p12 : hsel;
    hsel = (j16 == 13) ? p13 : hsel; hsel = (j16 == 14) ? p14 : hsel;
    hsel = (j16 == 15) ? p15 : hsel;
    float fh0, fh1, fh2, fh3, fh4, fh5, fh6, fh7;
    feat8s(hsel, fh0, fh1, fh2, fh3, fh4, fh5, fh6, fh7);
    // KAN1: broadcast hidden-j features from lane j via readlane (uniform)
    float accLo = 0.f, accHi = 0.f;
#define K1(J)                                                                  \
    {                                                                          \
      float q0 = RL(fh0, J), q1 = RL(fh1, J), q2 = RL(fh2, J), q3 = RL(fh3, J);\
      float q4 = RL(fh4, J), q5 = RL(fh5, J), q6 = RL(fh6, J), q7 = RL(fh7, J);\
      uint4 ra = *(const uint4*)&P1s[(J) * 512 + o * 4];                       \
      uint4 rb = *(const uint4*)&P1s[(J) * 512 + (o + 64) * 4];                \
      accLo = dot8s(ra, q0, q1, q2, q3, q4, q5, q6, q7, accLo);                \
      accHi = dot8s(rb, q0, q1, q2, q3, q4, q5, q6, q7, accHi);                \
    }
    REP16(K1)
#undef K1
    out[(size_t)node * C + o] = accLo;
    out[(size_t)node * C + o + 64] = accHi;
  }
}

extern "C" void kernel_launch(void* const* d_in, const int* in_sizes, int n_in,
                              void* d_out, int out_size, void* d_ws, size_t ws_size,
                              hipStream_t stream) {
  const float* x   = (const float*)d_in[0];
  const int*   ei  = (const int*)d_in[1];
  const float* gw  = (const float*)d_in[2];
  const float* gb  = (const float*)d_in[3];
  const float* bw0 = (const float*)d_in[4];
  const float* sw0 = (const float*)d_in[5];
  const float* sc0 = (const float*)d_in[6];
  const float* bw1 = (const float*)d_in[7];
  const float* sw1 = (const float*)d_in[8];
  const float* sc1 = (const float*)d_in[9];
  float* out = (float*)d_out;

  char* p = (char*)d_ws;
  float* Wt = (float*)p;      p += C * C * 4;
  u16* p0bf = (u16*)p;        p += H * C * 8 * 2;
  u16* p1bf = (u16*)p;        p += C * H * 8 * 2;
  float* dinv = (float*)p;    p += NN * 4;
  int* cnt = (int*)p;         p += NN * 4;
  int* excl = (int*)p;        p += NN * 4;
  int* fillcnt = (int*)p;     p += NN * 4;
  int* bsums = (int*)p;       p += 256 * 4;
  int* row_start = (int*)p;   p += (NN + 4) * 4;
  int* csr = (int*)p;         p += (size_t)NE * 4;
  float* csrw = (float*)p;    p += (size_t)NE * 4;
  float* axh = (float*)p;     p += (size_t)NN * C * 4;

  const int* src = ei;
  const int* dst = ei + NE;

  hipMemsetAsync(cnt, 0, NN * 4, stream);
  hipMemsetAsync(fillcnt, 0, NN * 4, stream);

  prep_kernel<<<64, 256, 0, stream>>>(gw, bw0, sw0, sc0, bw1, sw1, sc1, Wt, p0bf, p1bf);
  count_kernel<<<(NE + 255) / 256, 256, 0, stream>>>(dst, cnt);
  scan1<<<196, 256, 0, stream>>>(cnt, excl, bsums, NN);
  scan2<<<1, 256, 0, stream>>>(bsums, 196);
  scan3<<<196, 256, 0, stream>>>(excl, bsums, cnt, row_start, dinv, NN);
  fill_kernel<<<(NE + 255) / 256, 256, 0, stream>>>(src, dst, row_start, dinv, fillcnt, csr, csrw);
  agg_kernel<<<NN / 2, 256, 0, stream>>>(x, csr, csrw, row_start, dinv, axh);
  gemm128<<<(NN + 63) / 64, 256, 0, stream>>>(Wt, axh);
  kanC<<<512, 512, 0, stream>>>(axh, gb, p0bf, p1bf, out);
}

// Round 8
// 333.259 us; speedup vs baseline: 9.0417x; 7.1126x over previous
//
#include <hip/hip_runtime.h>
#include <hip/hip_bf16.h>

#define NN 50000
#define NE 800000
#define C 128
#define H 16

typedef unsigned int u32;
typedef unsigned short u16;

// ---------- silu + 7 cubic B-spline bases, closed form, NAMED outputs ----------
__device__ __forceinline__ void feat8s(float x, float& s, float& g0, float& g1,
                                       float& g2, float& g3, float& g4, float& g5,
                                       float& g6) {
  s = x / (1.f + __expf(-x));
  float t = (x + 2.5f) * 2.0f;
  float cf = floorf(t);
  int c = (int)cf;
  float u = t - cf;
  float u2 = u * u, u3 = u2 * u;
  const float k6 = 1.f / 6.f;
  float P0 = u3 * k6;
  float P1 = (1.f + 3.f * u + 3.f * u2 - 3.f * u3) * k6;
  float P2 = (4.f - 6.f * u2 + 3.f * u3) * k6;
  float om = 1.f - u;
  float P3 = om * om * om * k6;
  bool valid = (t >= 0.f) && (t < 10.f);
#define SPJ(G, J)                                   \
  {                                                 \
    float b = 0.f;                                  \
    b = (c == (J)) ? P0 : b;                        \
    b = (c == (J) + 1) ? P1 : b;                    \
    b = (c == (J) + 2) ? P2 : b;                    \
    b = (c == (J) + 3) ? P3 : b;                    \
    G = valid ? b : 0.f;                            \
  }
  SPJ(g0, 0) SPJ(g1, 1) SPJ(g2, 2) SPJ(g3, 3) SPJ(g4, 4) SPJ(g5, 5) SPJ(g6, 6)
#undef SPJ
}

__device__ __forceinline__ u16 f2bf(float v) {
  u32 b = __float_as_uint(v);
  return (u16)((b + 0x7fffu + ((b >> 16) & 1u)) >> 16);  // RNE
}

// dot of 8 bf16 weights (packed in uint4) with 8 named floats
__device__ __forceinline__ float dot8s(uint4 r, float f0, float f1, float f2,
                                       float f3, float f4, float f5, float f6,
                                       float f7, float acc) {
  acc = fmaf(__uint_as_float(r.x << 16), f0, acc);
  acc = fmaf(__uint_as_float(r.x & 0xffff0000u), f1, acc);
  acc = fmaf(__uint_as_float(r.y << 16), f2, acc);
  acc = fmaf(__uint_as_float(r.y & 0xffff0000u), f3, acc);
  acc = fmaf(__uint_as_float(r.z << 16), f4, acc);
  acc = fmaf(__uint_as_float(r.z & 0xffff0000u), f5, acc);
  acc = fmaf(__uint_as_float(r.w << 16), f6, acc);
  acc = fmaf(__uint_as_float(r.w & 0xffff0000u), f7, acc);
  return acc;
}

#define RL(x, J) __int_as_float(__builtin_amdgcn_readlane(__float_as_int(x), (J)))
#define REP16(M) M(0) M(1) M(2) M(3) M(4) M(5) M(6) M(7) M(8) M(9) M(10) M(11) M(12) M(13) M(14) M(15)

// ---------- prep: Wt transpose (f32) + bf16 packed KAN weights ----------
__global__ void prep_kernel(const float* __restrict__ W,
                            const float* __restrict__ bw0, const float* __restrict__ sw0,
                            const float* __restrict__ sc0,
                            const float* __restrict__ bw1, const float* __restrict__ sw1,
                            const float* __restrict__ sc1,
                            float* __restrict__ Wt, u16* __restrict__ p0bf,
                            u16* __restrict__ p1bf) {
  int i = blockIdx.x * blockDim.x + threadIdx.x;
  if (i < C * C) {
    int k = i >> 7, o = i & 127;
    Wt[k * C + o] = W[o * C + k];
  }
  if (i < H * C * 8) {
    int of = i >> 3, j = i & 7;
    float v = (j == 0) ? bw0[of] : sw0[of * 7 + (j - 1)] * sc0[of];
    p0bf[i] = f2bf(v);
  }
  if (i < C * H * 8) {
    int of = i >> 3, j = i & 7;
    float v = (j == 0) ? bw1[of] : sw1[of * 7 + (j - 1)] * sc1[of];
    p1bf[i] = f2bf(v);
  }
}

// ---------- in-degree count ----------
__global__ void count_kernel(const int* __restrict__ dst, int* __restrict__ cnt) {
  int e = blockIdx.x * blockDim.x + threadIdx.x;
  if (e < NE) atomicAdd(&cnt[dst[e]], 1);
}

// ---------- hierarchical exclusive scan ----------
__global__ void scan1(const int* __restrict__ cnt, int* __restrict__ excl,
                      int* __restrict__ bsums, int n) {
  int i = blockIdx.x * 256 + threadIdx.x;
  int v = (i < n) ? cnt[i] : 0;
  int lane = threadIdx.x & 63, wid = threadIdx.x >> 6;
  int s = v;
#pragma unroll
  for (int o = 1; o < 64; o <<= 1) {
    int t = __shfl_up(s, o, 64);
    if (lane >= o) s += t;
  }
  __shared__ int wsum[4];
  if (lane == 63) wsum[wid] = s;
  __syncthreads();
  int woff = 0;
  for (int w = 0; w < wid; ++w) woff += wsum[w];
  if (i < n) excl[i] = woff + s - v;
  if (threadIdx.x == 255) bsums[blockIdx.x] = woff + s;
}

__global__ void scan2(int* __restrict__ bsums, int nb) {
  int i = threadIdx.x;
  int v = (i < nb) ? bsums[i] : 0;
  int lane = threadIdx.x & 63, wid = threadIdx.x >> 6;
  int s = v;
#pragma unroll
  for (int o = 1; o < 64; o <<= 1) {
    int t = __shfl_up(s, o, 64);
    if (lane >= o) s += t;
  }
  __shared__ int wsum[4];
  if (lane == 63) wsum[wid] = s;
  __syncthreads();
  int woff = 0;
  for (int w = 0; w < wid; ++w) woff += wsum[w];
  if (i < nb) bsums[i] = woff + s - v;
}

__global__ void scan3(const int* __restrict__ excl, const int* __restrict__ bsums,
                      const int* __restrict__ cnt, int* __restrict__ row_start,
                      float* __restrict__ dinv, int n) {
  int i = blockIdx.x * 256 + threadIdx.x;
  if (i < n) {
    row_start[i] = excl[i] + bsums[blockIdx.x];
    dinv[i] = rsqrtf((float)(cnt[i] + 1));
  }
  if (blockIdx.x == 0 && threadIdx.x == 0) row_start[n] = NE;
}

// ---------- CSR fill; csrw = dinv[src]*dinv[dst] ----------
__global__ void fill_kernel(const int* __restrict__ src, const int* __restrict__ dst,
                            const int* __restrict__ row_start, const float* __restrict__ dinv,
                            int* __restrict__ fillcnt, int* __restrict__ csr,
                            float* __restrict__ csrw) {
  int e = blockIdx.x * blockDim.x + threadIdx.x;
  if (e < NE) {
    int d = dst[e];
    int s = src[e];
    int p = atomicAdd(&fillcnt[d], 1);
    int slot = row_start[d] + p;
    csr[slot] = s;
    csrw[slot] = dinv[s] * dinv[d];
  }
}

// ---------- aggregation ----------
__global__ __launch_bounds__(256, 8) void agg_kernel(
    const float* __restrict__ x, const int* __restrict__ csr,
    const float* __restrict__ csrw, const int* __restrict__ row_start,
    const float* __restrict__ dinv, float* __restrict__ ax) {
  const int c = threadIdx.x & 127;
  const int node = blockIdx.x * 2 + (threadIdx.x >> 7);
  const int e0 = row_start[node], e1 = row_start[node + 1];
  const float dn = dinv[node];
  float a = x[(size_t)node * C + c] * (dn * dn);
  int e = e0;
  for (; e + 4 <= e1; e += 4) {
    const int s0 = csr[e], s1 = csr[e + 1], s2 = csr[e + 2], s3 = csr[e + 3];
    const float w0 = csrw[e], w1 = csrw[e + 1], w2 = csrw[e + 2], w3 = csrw[e + 3];
    a += x[(size_t)s0 * C + c] * w0;
    a += x[(size_t)s1 * C + c] * w1;
    a += x[(size_t)s2 * C + c] * w2;
    a += x[(size_t)s3 * C + c] * w3;
  }
  for (; e < e1; ++e) a += x[(size_t)csr[e] * C + c] * csrw[e];
  ax[(size_t)node * C + c] = a;
}

// ---------- GEMV as tiled GEMM, in-place: h = ax @ W^T ----------
__global__ __launch_bounds__(256) void gemm128(const float* __restrict__ Wt,
                                               float* __restrict__ axh) {
  __shared__ float Xs[64][129];
  __shared__ float Ws[32][132];
  const int tid = threadIdx.x;
  const int n0 = blockIdx.x * 64;
#pragma unroll
  for (int it = 0; it < 8; ++it) {
    int idx = it * 1024 + tid * 4;
    int n = idx >> 7, k = idx & 127;
    float4 v = make_float4(0.f, 0.f, 0.f, 0.f);
    if (n0 + n < NN) v = *(const float4*)&axh[(size_t)(n0 + n) * C + k];
    *(float4*)&Xs[n][k] = v;
  }
  const int nt = tid & 15, ot = tid >> 4;
  float4 accA[4], accB[4];
#pragma unroll
  for (int d = 0; d < 4; ++d) {
    accA[d] = make_float4(0.f, 0.f, 0.f, 0.f);
    accB[d] = make_float4(0.f, 0.f, 0.f, 0.f);
  }
  for (int k0 = 0; k0 < 128; k0 += 32) {
    __syncthreads();
#pragma unroll
    for (int it = 0; it < 4; ++it) {
      int idx = it * 1024 + tid * 4;
      int k = idx >> 7, oo = idx & 127;
      *(float4*)&Ws[k][oo] = *(const float4*)&Wt[(k0 + k) * C + oo];
    }
    __syncthreads();
#pragma unroll
    for (int k = 0; k < 32; ++k) {
      float4 w0 = *(const float4*)&Ws[k][ot * 8];
      float4 w1 = *(const float4*)&Ws[k][ot * 8 + 4];
#pragma unroll
      for (int d = 0; d < 4; ++d) {
        float xv = Xs[nt * 4 + d][k0 + k];
        accA[d].x += xv * w0.x; accA[d].y += xv * w0.y;
        accA[d].z += xv * w0.z; accA[d].w += xv * w0.w;
        accB[d].x += xv * w1.x; accB[d].y += xv * w1.y;
        accB[d].z += xv * w1.z; accB[d].w += xv * w1.w;
      }
    }
  }
#pragma unroll
  for (int d = 0; d < 4; ++d) {
    int node = n0 + nt * 4 + d;
    if (node < NN) {
      *(float4*)&axh[(size_t)node * C + ot * 8] = accA[d];
      *(float4*)&axh[(size_t)node * C + ot * 8 + 4] = accB[d];
    }
  }
}

// ---------- KAN stack v3: fused K0+butterfly+select per J (tiny live set) ----------
// r7 lesson: p0..p15 + 32 hoisted uint4 LDS loads blew past 128 VGPR -> spill.
// Here each J-block computes its partial, reduces it, folds into hsel, and a
// sched_barrier(0) stops the scheduler from hoisting loads across blocks.
__global__ __launch_bounds__(512) void kanD(
    const float* __restrict__ h, const float* __restrict__ bias,
    const u16* __restrict__ p0bf, const u16* __restrict__ p1bf,
    float* __restrict__ out) {
  __shared__ u32 P0s[8192];   // 32 KB: uint4 idx j*128 + f
  __shared__ u32 P1s[8192];   // 32 KB: uint4 idx j*128 + o
  const int tid = threadIdx.x;
  {
    const uint4* g0 = (const uint4*)p0bf;  // record r = j*128 + f (matches)
    const uint4* g1 = (const uint4*)p1bf;  // record r = o*16 + j -> transpose
    uint4* s0 = (uint4*)P0s;
    uint4* s1 = (uint4*)P1s;
    for (int r = tid; r < 2048; r += 512) {
      s0[r] = g0[r];
      int o = r >> 4, j = r & 15;
      s1[j * 128 + o] = g1[r];
    }
  }
  __syncthreads();
  const int o = tid & 63;
  const int wave = tid >> 6;
  const int j16 = o & 15;
  const float bLo = bias[o], bHi = bias[o + 64];
  for (int node = blockIdx.x * 8 + wave; node < NN; node += 4096) {
    float fa0, fa1, fa2, fa3, fa4, fa5, fa6, fa7;
    float fb0, fb1, fb2, fb3, fb4, fb5, fb6, fb7;
    feat8s(h[(size_t)node * C + o] + bLo, fa0, fa1, fa2, fa3, fa4, fa5, fa6, fa7);
    feat8s(h[(size_t)node * C + o + 64] + bHi, fb0, fb1, fb2, fb3, fb4, fb5, fb6, fb7);
    // per-J: partial dot -> full 64-lane butterfly -> select into hsel.
    // v dies inside the block; nothing but hsel survives.
    float hsel = 0.f;
#define K0BF(J)                                                                \
    {                                                                          \
      uint4 ra = *(const uint4*)&P0s[(J) * 512 + o * 4];                       \
      uint4 rb = *(const uint4*)&P0s[(J) * 512 + (o + 64) * 4];                \
      float v = dot8s(ra, fa0, fa1, fa2, fa3, fa4, fa5, fa6, fa7, 0.f);        \
      v = dot8s(rb, fb0, fb1, fb2, fb3, fb4, fb5, fb6, fb7, v);                \
      v += __shfl_xor(v, 1, 64);  v += __shfl_xor(v, 2, 64);                   \
      v += __shfl_xor(v, 4, 64);  v += __shfl_xor(v, 8, 64);                   \
      v += __shfl_xor(v, 16, 64); v += __shfl_xor(v, 32, 64);                  \
      hsel = (j16 == (J)) ? v : hsel;                                          \
      __builtin_amdgcn_sched_barrier(0);                                       \
    }
    REP16(K0BF)
#undef K0BF
    // lane o now holds hidden value j16 = o&15 (replicated x4 across the wave)
    float fh0, fh1, fh2, fh3, fh4, fh5, fh6, fh7;
    feat8s(hsel, fh0, fh1, fh2, fh3, fh4, fh5, fh6, fh7);
    // KAN1: broadcast hidden-j features from lane j via readlane (uniform)
    float accLo = 0.f, accHi = 0.f;
#define K1(J)                                                                  \
    {                                                                          \
      float q0 = RL(fh0, J), q1 = RL(fh1, J), q2 = RL(fh2, J), q3 = RL(fh3, J);\
      float q4 = RL(fh4, J), q5 = RL(fh5, J), q6 = RL(fh6, J), q7 = RL(fh7, J);\
      uint4 ra = *(const uint4*)&P1s[(J) * 512 + o * 4];                       \
      uint4 rb = *(const uint4*)&P1s[(J) * 512 + (o + 64) * 4];                \
      accLo = dot8s(ra, q0, q1, q2, q3, q4, q5, q6, q7, accLo);                \
      accHi = dot8s(rb, q0, q1, q2, q3, q4, q5, q6, q7, accHi);                \
      __builtin_amdgcn_sched_barrier(0);                                       \
    }
    REP16(K1)
#undef K1
    out[(size_t)node * C + o] = accLo;
    out[(size_t)node * C + o + 64] = accHi;
  }
}

extern "C" void kernel_launch(void* const* d_in, const int* in_sizes, int n_in,
                              void* d_out, int out_size, void* d_ws, size_t ws_size,
                              hipStream_t stream) {
  const float* x   = (const float*)d_in[0];
  const int*   ei  = (const int*)d_in[1];
  const float* gw  = (const float*)d_in[2];
  const float* gb  = (const float*)d_in[3];
  const float* bw0 = (const float*)d_in[4];
  const float* sw0 = (const float*)d_in[5];
  const float* sc0 = (const float*)d_in[6];
  const float* bw1 = (const float*)d_in[7];
  const float* sw1 = (const float*)d_in[8];
  const float* sc1 = (const float*)d_in[9];
  float* out = (float*)d_out;

  char* p = (char*)d_ws;
  float* Wt = (float*)p;      p += C * C * 4;
  u16* p0bf = (u16*)p;        p += H * C * 8 * 2;
  u16* p1bf = (u16*)p;        p += C * H * 8 * 2;
  float* dinv = (float*)p;    p += NN * 4;
  int* cnt = (int*)p;         p += NN * 4;
  int* excl = (int*)p;        p += NN * 4;
  int* fillcnt = (int*)p;     p += NN * 4;
  int* bsums = (int*)p;       p += 256 * 4;
  int* row_start = (int*)p;   p += (NN + 4) * 4;
  int* csr = (int*)p;         p += (size_t)NE * 4;
  float* csrw = (float*)p;    p += (size_t)NE * 4;
  float* axh = (float*)p;     p += (size_t)NN * C * 4;

  const int* src = ei;
  const int* dst = ei + NE;

  hipMemsetAsync(cnt, 0, NN * 4, stream);
  hipMemsetAsync(fillcnt, 0, NN * 4, stream);

  prep_kernel<<<64, 256, 0, stream>>>(gw, bw0, sw0, sc0, bw1, sw1, sc1, Wt, p0bf, p1bf);
  count_kernel<<<(NE + 255) / 256, 256, 0, stream>>>(dst, cnt);
  scan1<<<196, 256, 0, stream>>>(cnt, excl, bsums, NN);
  scan2<<<1, 256, 0, stream>>>(bsums, 196);
  scan3<<<196, 256, 0, stream>>>(excl, bsums, cnt, row_start, dinv, NN);
  fill_kernel<<<(NE + 255) / 256, 256, 0, stream>>>(src, dst, row_start, dinv, fillcnt, csr, csrw);
  agg_kernel<<<NN / 2, 256, 0, stream>>>(x, csr, csrw, row_start, dinv, axh);
  gemm128<<<(NN + 63) / 64, 256, 0, stream>>>(Wt, axh);
  kanD<<<512, 512, 0, stream>>>(axh, gb, p0bf, p1bf, out);
}